// Round 14
// baseline (566.150 us; speedup 1.0000x reference)
//
#include <hip/hip_runtime.h>

typedef unsigned short u16;
typedef __bf16 bf16x8 __attribute__((ext_vector_type(8)));
typedef float f32x4 __attribute__((ext_vector_type(4)));
typedef unsigned u32x4 __attribute__((ext_vector_type(4)));

#define S_LEN 2048
#define HID 5120
#define NHEAD 40
#define NKVH 8
#define HD 128
#define QKV_COLS 7168   // (40 + 2*8) * 128
#define GQA 5
#define QBLK 128
#define KVBLK 64
#define NQT (S_LEN / QBLK)        // 16
#define NITEMS (NQT * NHEAD)      // 640

// RNE f32 -> bf16
__device__ __forceinline__ u16 f2bf(float f) {
  unsigned u = __float_as_uint(f);
  u += 0x7FFFu + ((u >> 16) & 1u);
  return (u16)(u >> 16);
}

// async global->LDS, 16B per lane; LDS base must be wave-uniform
__device__ __forceinline__ void async16(void* lds, const void* g) {
  __builtin_amdgcn_global_load_lds(
      (const __attribute__((address_space(1))) unsigned int*)g,
      (__attribute__((address_space(3))) unsigned int*)lds, 16, 0, 0);
}

// ---------- f32 -> bf16 elementwise convert ----------
__global__ void k_f32_to_bf16(const float4* __restrict__ in, uint2* __restrict__ out, int n4) {
  int i = blockIdx.x * blockDim.x + threadIdx.x;
  int stride = gridDim.x * blockDim.x;
  for (; i < n4; i += stride) {
    float4 v = in[i];
    uint2 o;
    o.x = (unsigned)f2bf(v.x) | ((unsigned)f2bf(v.y) << 16);
    o.y = (unsigned)f2bf(v.z) | ((unsigned)f2bf(v.w) << 16);
    out[i] = o;
  }
}

// ---------- 128x128 GEMM, r12-proven schedule, 2 blocks/CU ----------
// Round-14: tile halved 256->128 to fix machine fill (grids were 224/160 on
// 256 CUs at 1 block/CU = 87%/62% fill; per-CU rate was identical 954 TF for
// both GEMMs). 64 KB LDS -> 2 blocks/CU; grids 896/640. Phase (r12 pattern):
// [ds_read][VM4@tile-q0][s_barrier][stage post-bar][prio 16 MFMA].
// vmcnt ledger (groups of 4): VM4 at each tile's q0 waits exactly that tile's
// A+B; stages: A(t+1)@t0q0, B(t+2)@t0q1, A(t+2)@t1q0, B(t+3)@t1q1.
// Peel: stage A(nkt-1) only; VM0 before last tile.
__global__ __launch_bounds__(256, 2)
void k_gemm128(const u16* __restrict__ A, const u16* __restrict__ B,
               float* __restrict__ C, int M, int N, int K) {
  __shared__ __align__(16) u16 As[2][128 * 64];   // 2 x 16 KB
  __shared__ __align__(16) u16 Bs[2][128 * 64];   // 2 x 16 KB  => 64 KB
  const int tid = threadIdx.x;
  const int wave = tid >> 6, lane = tid & 63;
  const int l15 = lane & 15, l4 = lane >> 4;
  const int wm = wave >> 1, wn = wave & 1;        // 2x2 waves, each 64x64

  const int nwg = gridDim.x;
  int f = blockIdx.x;
  int swz = (nwg % 8 == 0) ? ((f & 7) * (nwg >> 3) + (f >> 3)) : f;
  // by-minor over 16 M-tiles: each XCD's contiguous swz chunk spans all
  // M-rows x ~(nwg/128) B-cols; A/B k-windows stay L2-resident.
  const int by = swz & 15, bx = swz >> 4;
  const int row0 = by * 128, col0 = bx * 128;

  const int srow = tid >> 3;                      // 0..31
  const int sgch = ((tid & 7) ^ (srow & 7)) * 8;  // inverse-swizzled global chunk
  const int s7 = l15 & 7;
  const int ch0 = (l4 ^ s7) * 8;                  // swizzled read chunks
  const int ch1 = ((4 + l4) ^ s7) * 8;

  f32x4 acc[4][4] = {};

#define STG_A(buf, kt)                                                              \
  do {                                                                              \
    const size_t k0_ = (size_t)(kt) * 64;                                           \
    _Pragma("unroll") for (int j = 0; j < 4; ++j)                                   \
      async16(&As[buf][(j * 32 + wave * 8) * 64],                                   \
              A + (size_t)(row0 + j * 32 + srow) * K + k0_ + sgch);                 \
  } while (0)
#define STG_B(buf, kt)                                                              \
  do {                                                                              \
    const size_t k0_ = (size_t)(kt) * 64;                                           \
    _Pragma("unroll") for (int j = 0; j < 4; ++j)                                   \
      async16(&Bs[buf][(j * 32 + wave * 8) * 64],                                   \
              B + (size_t)(col0 + j * 32 + srow) * K + k0_ + sgch);                 \
  } while (0)

#define PH(buf, q, STAGE, VM)                                                       \
  {                                                                                 \
    bf16x8 af[2][2];                                                                \
    _Pragma("unroll") for (int e = 0; e < 2; ++e) {                                 \
      const u16* pa = &As[buf][(wm * 64 + (2 * (q) + e) * 16 + l15) * 64];          \
      af[e][0] = *(const bf16x8*)(pa + ch0);                                        \
      af[e][1] = *(const bf16x8*)(pa + ch1);                                        \
    }                                                                               \
    if ((q) == 0) {                                                                 \
      _Pragma("unroll") for (int n = 0; n < 4; ++n) {                               \
        const u16* pb = &Bs[buf][(wn * 64 + n * 16 + l15) * 64];                    \
        bfr[n][0] = *(const bf16x8*)(pb + ch0);                                     \
        bfr[n][1] = *(const bf16x8*)(pb + ch1);                                     \
      }                                                                             \
    }                                                                               \
    VM;                                                                             \
    __builtin_amdgcn_s_barrier();                                                   \
    STAGE;                                                                          \
    __builtin_amdgcn_s_setprio(1);                                                  \
    _Pragma("unroll") for (int kk = 0; kk < 2; ++kk)                                \
      _Pragma("unroll") for (int e = 0; e < 2; ++e)                                 \
        _Pragma("unroll") for (int n = 0; n < 4; ++n)                               \
          acc[2 * (q) + e][n] = __builtin_amdgcn_mfma_f32_16x16x32_bf16(            \
              af[e][kk], bfr[n][kk], acc[2 * (q) + e][n], 0, 0, 0);                 \
    __builtin_amdgcn_s_setprio(0);                                                  \
  }
#define VM4 asm volatile("s_waitcnt vmcnt(4)" ::: "memory")
#define VM0 asm volatile("s_waitcnt vmcnt(0)" ::: "memory")
#define VMNONE

  const int nkt = K >> 6;       // K-tiles of 64 (even, >= 4)
  const int niter = nkt >> 1;

  // prologue: A(t0),B(t0)->buf0; B(t1)->buf1; drain tile0, keep B(t1) flying
  STG_A(0, 0); STG_B(0, 0); STG_B(1, 1);
  VM4;
  __builtin_amdgcn_s_barrier();

  // main loop (stages unguarded: i+1 < niter => 2i+3 <= nkt-1)
  for (int i = 0; i + 1 < niter; ++i) {
    bf16x8 bfr[4][2];
    PH(0, 0, STG_A(1, 2 * i + 1), VM4)
    PH(0, 1, STG_B(0, 2 * i + 2), VMNONE)
    PH(1, 0, STG_A(0, 2 * i + 2), VM4)
    PH(1, 1, STG_B(1, 2 * i + 3), VMNONE)
  }
  // peeled final pair
  {
    bf16x8 bfr[4][2];
    PH(0, 0, STG_A(1, nkt - 1), VM4)
    PH(0, 1, ((void)0), VMNONE)
    PH(1, 0, ((void)0), VM0)
    PH(1, 1, ((void)0), VMNONE)
  }

#pragma unroll
  for (int m = 0; m < 4; ++m)
#pragma unroll
    for (int n = 0; n < 4; ++n)
#pragma unroll
      for (int r = 0; r < 4; ++r) {
        int row = row0 + wm * 64 + m * 16 + l4 * 4 + r;
        int col = col0 + wn * 64 + n * 16 + l15;
        C[(size_t)row * N + col] = acc[m][n][r];
      }
#undef STG_A
#undef STG_B
#undef PH
#undef VM4
#undef VM0
#undef VMNONE
}

// ---------- RoPE (neox) + per-head RMSNorm ----------
__global__ void k_rope_norm(const float* __restrict__ qkv, const int* __restrict__ pos,
                            const float* __restrict__ wqk,
                            u16* __restrict__ qo, u16* __restrict__ ko) {
  const int wid = (blockIdx.x * blockDim.x + threadIdx.x) >> 6;
  const int lane = threadIdx.x & 63;
  const int s = wid / 48;
  const int r = wid - s * 48;
  const float* src;
  u16* dst;
  const bool isq = (r < NHEAD);
  if (isq) {
    src = qkv + (size_t)s * QKV_COLS + r * HD;
    dst = qo + (size_t)s * (NHEAD * HD) + r * HD;
  } else {
    int kv = r - NHEAD;
    src = qkv + (size_t)s * QKV_COLS + HID + kv * HD;
    dst = ko + (size_t)s * (NKVH * HD) + kv * HD;
  }
  float x1 = src[lane], x2 = src[lane + 64];
  float p = (float)pos[s];
  float ang = p * exp2f(-(float)lane * (18.931568569324174f / 64.0f));
  float sn, cs;
  sincosf(ang, &sn, &cs);
  float y1 = x1 * cs - x2 * sn;
  float y2 = x2 * cs + x1 * sn;
  float ss = y1 * y1 + y2 * y2;
#pragma unroll
  for (int off = 32; off > 0; off >>= 1) ss += __shfl_xor(ss, off);
  float rms = rsqrtf(ss * (1.0f / 128.0f) + 1e-5f);
  float sc = isq ? 0.08838834764831843f : 1.0f;
  dst[lane] = f2bf(y1 * rms * wqk[lane] * sc);
  dst[lane + 64] = f2bf(y2 * rms * wqk[lane + 64] * sc);
}

// ---------- V: [s][6144 + kvh*128 + d] f32 -> Vt[kvh][d][s] bf16 ----------
__global__ void k_vtrans(const float* __restrict__ qkv, u16* __restrict__ vt) {
  __shared__ float t[32][129];
  const int s0 = blockIdx.x * 32;
  const int kv = blockIdx.y;
  for (int i = threadIdx.x; i < 32 * 128; i += 256) {
    int sr = i >> 7, d = i & 127;
    t[sr][d] = qkv[(size_t)(s0 + sr) * QKV_COLS + (HID + NKVH * HD) + kv * HD + d];
  }
  __syncthreads();
  for (int i = threadIdx.x; i < 32 * 128; i += 256) {
    int d = i >> 5, sc = i & 31;
    vt[((size_t)kv * HD + d) * S_LEN + s0 + sc] = f2bf(t[sc][d]);
  }
}

// ---------- causal GQA flash attention: persistent blocks + atomic LPT queue ----------
__global__ __launch_bounds__(256, 2)
void k_attn(const u16* __restrict__ Q, const u16* __restrict__ Kb,
            const u16* __restrict__ Vt, u16* __restrict__ ctx,
            int* __restrict__ counter) {
  __shared__ __align__(16) u16 Ks[2][KVBLK * HD];
  __shared__ __align__(16) u16 Vs[2][HD * KVBLK];
  __shared__ int s_item;
  const int lane = threadIdx.x & 63;
  const int wave = threadIdx.x >> 6;
  const int l15 = lane & 15, l4 = lane >> 4;
  const int l7 = lane & 7, l8 = lane >> 3;

#define STAGE_KV(KT, BUF, KVH)                                                      \
  do {                                                                             \
    const int key0_ = (KT) * KVBLK;                                                \
    _Pragma("unroll")                                                              \
    for (int i = 0; i < 4; ++i) {                                                  \
      int krow = wave * 16 + i * 4 + l4;                                           \
      int kchunk = l15 ^ (krow & 7);                                               \
      async16(&Ks[BUF][(wave * 16 + i * 4) * HD],                                  \
              Kb + (size_t)(key0_ + krow) * (NKVH * HD) + (KVH) * HD + kchunk * 8);\
    }                                                                              \
    _Pragma("unroll")                                                              \
    for (int i = 0; i < 4; ++i) {                                                  \
      int vrow = wave * 32 + i * 8 + l8;                                           \
      int vchunk = l7 ^ (vrow & 7);                                                \
      async16(&Vs[BUF][(wave * 32 + i * 8) * KVBLK],                               \
              Vt + (size_t)((KVH) * HD + vrow) * S_LEN + key0_ + vchunk * 8);      \
    }                                                                              \
  } while (0)

#define VM8 asm volatile("s_waitcnt vmcnt(8)" ::: "memory")
#define VM0 asm volatile("s_waitcnt vmcnt(0)" ::: "memory")
#define BAR __builtin_amdgcn_s_barrier(); __builtin_amdgcn_sched_barrier(0)

#define COMPUTE(BUF, KT)                                                           \
  {                                                                                \
    const int key0 = (KT) * KVBLK;                                                 \
    f32x4 sa[2][4] = {};                                                           \
    _Pragma("unroll")                                                              \
    for (int c = 0; c < 4; ++c) {                                                  \
      _Pragma("unroll")                                                            \
      for (int n = 0; n < 4; ++n) {                                                \
        const int krow = n * 16 + l15;                                             \
        bf16x8 kf = *(const bf16x8*)(&Ks[BUF][krow * HD + ((c * 4 + l4) ^ (krow & 7)) * 8]); \
        sa[0][n] = __builtin_amdgcn_mfma_f32_16x16x32_bf16(kf, qf[0][c], sa[0][n], 0, 0, 0); \
        sa[1][n] = __builtin_amdgcn_mfma_f32_16x16x32_bf16(kf, qf[1][c], sa[1][n], 0, 0, 0); \
      }                                                                            \
    }                                                                              \
    const bool domask = (key0 + KVBLK) > qt * QBLK;                                \
    bf16x8 pa[2][2];                                                               \
    _Pragma("unroll")                                                              \
    for (int m2 = 0; m2 < 2; ++m2) {                                               \
      const int qrow = qrow0 + m2 * 16 + l15;                                      \
      if (domask) {                                                                \
        _Pragma("unroll")                                                          \
        for (int n = 0; n < 4; ++n)                                                \
          _Pragma("unroll")                                                        \
          for (int r = 0; r < 4; ++r)                                              \
            if (key0 + n * 16 + l4 * 4 + r > qrow) sa[m2][n][r] = -1e30f;          \
      }                                                                            \
      float mx = sa[m2][0][0];                                                     \
      _Pragma("unroll")                                                            \
      for (int n = 0; n < 4; ++n)                                                  \
        _Pragma("unroll")                                                          \
        for (int r = 0; r < 4; ++r) mx = fmaxf(mx, sa[m2][n][r]);                  \
      mx = fmaxf(mx, __shfl_xor(mx, 16));                                          \
      mx = fmaxf(mx, __shfl_xor(mx, 32));                                          \
      const float mnew = fmaxf(m_run[m2], mx);                                     \
      const float corr = __expf(m_run[m2] - mnew);                                 \
      m_run[m2] = mnew;                                                            \
      float p[4][4];                                                               \
      float sum = 0.f;                                                             \
      _Pragma("unroll")                                                            \
      for (int n = 0; n < 4; ++n)                                                  \
        _Pragma("unroll")                                                          \
        for (int r = 0; r < 4; ++r) { p[n][r] = __expf(sa[m2][n][r] - mnew); sum += p[n][r]; } \
      sum += __shfl_xor(sum, 16);                                                  \
      sum += __shfl_xor(sum, 32);                                                  \
      l_run[m2] = l_run[m2] * corr + sum;                                          \
      _Pragma("unroll")                                                            \
      for (int r = 0; r < 4; ++r) {                                                \
        float cc = __shfl(corr, (lane & 48) + ((lane >> 4) << 2) + r);             \
        _Pragma("unroll")                                                          \
        for (int f2 = 0; f2 < 8; ++f2) oacc[m2][f2][r] *= cc;                      \
      }                                                                            \
      unsigned pkk[4][2];                                                          \
      _Pragma("unroll")                                                            \
      for (int n = 0; n < 4; ++n)                                                  \
        _Pragma("unroll")                                                          \
        for (int hi = 0; hi < 2; ++hi)                                             \
          pkk[n][hi] = (unsigned)f2bf(p[n][2 * hi]) | ((unsigned)f2bf(p[n][2 * hi + 1]) << 16); \
      const int s0l = ((lane >> 4) & 1) * 32 + (lane & 15);                        \
      const bool hiSel = (lane & 32) != 0;                                         \
      _Pragma("unroll")                                                            \
      for (int c2 = 0; c2 < 2; ++c2) {                                             \
        unsigned ox[4];                                                            \
        _Pragma("unroll")                                                          \
        for (int i = 0; i < 4; ++i) {                                              \
          int srcl = s0l + ((i >> 1) << 4);                                        \
          unsigned lo = (unsigned)__shfl((int)pkk[2 * c2][i & 1], srcl);           \
          unsigned hi2 = (unsigned)__shfl((int)pkk[2 * c2 + 1][i & 1], srcl);      \
          ox[i] = hiSel ? hi2 : lo;                                                \
        }                                                                          \
        u32x4 tmp = {ox[0], ox[1], ox[2], ox[3]};                                  \
        pa[m2][c2] = __builtin_bit_cast(bf16x8, tmp);                              \
      }                                                                            \
    }                                                                              \
    _Pragma("unroll")                                                              \
    for (int c2 = 0; c2 < 2; ++c2) {                                               \
      _Pragma("unroll")                                                            \
      for (int f2 = 0; f2 < 8; ++f2) {                                             \
        const int vrow = f2 * 16 + l15;                                            \
        bf16x8 vf = *(const bf16x8*)(&Vs[BUF][vrow * KVBLK + ((c2 * 4 + l4) ^ (vrow & 7)) * 8]); \
        oacc[0][f2] = __builtin_amdgcn_mfma_f32_16x16x32_bf16(pa[0][c2], vf, oacc[0][f2], 0, 0, 0); \
        oacc[1][f2] = __builtin_amdgcn_mfma_f32_16x16x32_bf16(pa[1][c2], vf, oacc[1][f2], 0, 0, 0); \
      }                                                                            \
    }                                                                              \
  }

  for (;;) {
    if (threadIdx.x == 0) s_item = atomicAdd(counter, 1);
    __syncthreads();   // also orders previous item's LDS reads before restage
    const int item = s_item;
    if (item >= NITEMS) break;
    const int qt = (NQT - 1) - item / NHEAD;   // heaviest-first (LPT)
    const int h = item % NHEAD;
    const int kvh = h / GQA;
    const int qrow0 = qt * QBLK + wave * 32;

    bf16x8 qf[2][4];
#pragma unroll
    for (int c = 0; c < 4; ++c)
#pragma unroll
      for (int m2 = 0; m2 < 2; ++m2)
        qf[m2][c] = *(const bf16x8*)(Q + (size_t)(qrow0 + m2 * 16 + l15) * HID + h * HD + c * 32 + l4 * 8);

    float m_run[2] = {-1e30f, -1e30f};
    float l_run[2] = {0.f, 0.f};
    f32x4 oacc[2][8] = {};

    const int nt = 2 * qt + 2;

    STAGE_KV(0, 0, kvh);
    STAGE_KV(1, 1, kvh);

    int t = 0;
    for (; t + 2 < nt; t += 2) {
      VM8; BAR;
      COMPUTE(0, t)
      BAR;
      STAGE_KV(t + 2, 0, kvh);
      VM8; BAR;
      COMPUTE(1, t + 1)
      BAR;
      if (t + 3 < nt) STAGE_KV(t + 3, 1, kvh);
    }
    VM8; BAR;
    COMPUTE(0, nt - 2)
    VM0; BAR;
    COMPUTE(1, nt - 1)

#pragma unroll
    for (int m2 = 0; m2 < 2; ++m2)
#pragma unroll
      for (int r = 0; r < 4; ++r) {
        float li = 1.0f / __shfl(l_run[m2], (lane & 48) + ((lane >> 4) << 2) + r);
        int row = qrow0 + m2 * 16 + l4 * 4 + r;
#pragma unroll
        for (int f2 = 0; f2 < 8; ++f2)
          ctx[(size_t)row * HID + h * HD + f2 * 16 + l15] = f2bf(oacc[m2][f2][r] * li);
      }
  }
#undef STAGE_KV
#undef VM8
#undef VM0
#undef BAR
#undef COMPUTE
}

extern "C" void kernel_launch(void* const* d_in, const int* in_sizes, int n_in,
                              void* d_out, int out_size, void* d_ws, size_t ws_size,
                              hipStream_t stream) {
  (void)in_sizes; (void)n_in; (void)out_size; (void)ws_size;
  const int* positions = (const int*)d_in[0];
  const float* hs = (const float*)d_in[1];
  const float* Wqkv = (const float*)d_in[2];
  const float* Wo = (const float*)d_in[3];
  const float* wqk = (const float*)d_in[4];
  float* out = (float*)d_out;

  char* ws = (char*)d_ws;
  u16* Wqkv_b = (u16*)ws;                  // [0, 73400320)  dead after GEMM1
  u16* q_b   = (u16*)ws;                   // reuse: [0, 20971520)
  u16* k_b   = (u16*)(ws + 20971520);      // [.., 25165824)
  u16* vt_b  = (u16*)(ws + 25165824);      // [.., 29360128)
  int* cnt   = (int*)(ws + 29360128);      // 4 B (dead Wqkv region at attn time)
  u16* Wo_b  = (u16*)(ws + 73400320);      // [.., 125829120)
  u16* hs_b  = (u16*)(ws + 125829120);     // [.., 146800640)  dead after GEMM1
  u16* ctx_b = hs_b;                       // reuse
  float* qkv = (float*)(ws + 146800640);   // [.., 205520896)

  k_f32_to_bf16<<<2048, 256, 0, stream>>>((const float4*)hs, (uint2*)hs_b, (S_LEN * HID) / 4);
  k_f32_to_bf16<<<2048, 256, 0, stream>>>((const float4*)Wqkv, (uint2*)Wqkv_b, (QKV_COLS * HID) / 4);
  k_f32_to_bf16<<<2048, 256, 0, stream>>>((const float4*)Wo, (uint2*)Wo_b, (HID * HID) / 4);

  k_gemm128<<<dim3((QKV_COLS / 128) * (S_LEN / 128)), 256, 0, stream>>>(
      hs_b, Wqkv_b, qkv, S_LEN, QKV_COLS, HID);

  k_rope_norm<<<(S_LEN * 48) / 4, 256, 0, stream>>>(qkv, positions, wqk, q_b, k_b);
  k_vtrans<<<dim3(S_LEN / 32, NKVH), 256, 0, stream>>>(qkv, vt_b);

  hipMemsetAsync(cnt, 0, 4, stream);
  k_attn<<<dim3(512), 256, 0, stream>>>(q_b, k_b, vt_b, ctx_b, cnt);

  k_gemm128<<<dim3((HID / 128) * (S_LEN / 128)), 256, 0, stream>>>(
      ctx_b, Wo_b, out, S_LEN, HID, HID);
}

// Round 15
// 485.835 us; speedup vs baseline: 1.1653x; 1.1653x over previous
//
#include <hip/hip_runtime.h>

typedef unsigned short u16;
typedef __bf16 bf16x8 __attribute__((ext_vector_type(8)));
typedef float f32x4 __attribute__((ext_vector_type(4)));
typedef unsigned u32x4 __attribute__((ext_vector_type(4)));

#define S_LEN 2048
#define HID 5120
#define NHEAD 40
#define NKVH 8
#define HD 128
#define QKV_COLS 7168   // (40 + 2*8) * 128
#define GQA 5
#define QBLK 128
#define KVBLK 64
#define NQT (S_LEN / QBLK)        // 16
#define NITEMS (NQT * NHEAD)      // 640

// RNE f32 -> bf16
__device__ __forceinline__ u16 f2bf(float f) {
  unsigned u = __float_as_uint(f);
  u += 0x7FFFu + ((u >> 16) & 1u);
  return (u16)(u >> 16);
}
// bf16 (as u16) -> f32
__device__ __forceinline__ float bf2f(u16 v) {
  return __uint_as_float(((unsigned)v) << 16);
}

// async global->LDS, 16B per lane; LDS base must be wave-uniform
__device__ __forceinline__ void async16(void* lds, const void* g) {
  __builtin_amdgcn_global_load_lds(
      (const __attribute__((address_space(1))) unsigned int*)g,
      (__attribute__((address_space(3))) unsigned int*)lds, 16, 0, 0);
}

// ---------- f32 -> bf16 elementwise convert ----------
__global__ void k_f32_to_bf16(const float4* __restrict__ in, uint2* __restrict__ out, int n4) {
  int i = blockIdx.x * blockDim.x + threadIdx.x;
  int stride = gridDim.x * blockDim.x;
  for (; i < n4; i += stride) {
    float4 v = in[i];
    uint2 o;
    o.x = (unsigned)f2bf(v.x) | ((unsigned)f2bf(v.y) << 16);
    o.y = (unsigned)f2bf(v.z) | ((unsigned)f2bf(v.w) << 16);
    out[i] = o;
  }
}

// ---------- 256x256 GEMM, r11-champion schedule (516.8 us config) ----------
// Phase: [ds_read][VM2@p3,p7][s_barrier][lgkm0 fence][stage post-bar]
// [prio 16 MFMA kk-outer]. by-minor XCD map. Round-15 delta: optional bf16
// C-write (runtime flag; epilogue only) for the qkv intermediate.
__global__ __launch_bounds__(512, 2)
void k_gemm256(const u16* __restrict__ A, const u16* __restrict__ B,
               float* __restrict__ C, u16* __restrict__ Cb,
               int M, int N, int K) {
  __shared__ __align__(16) u16 As[2][2][128 * 64];
  __shared__ __align__(16) u16 Bs[2][2][128 * 64];
  const int tid = threadIdx.x;
  const int wave = tid >> 6, lane = tid & 63;
  const int l15 = lane & 15, l4 = lane >> 4;
  const int wm = wave >> 2, wn = wave & 3;

  const int nwg = gridDim.x;
  int f = blockIdx.x;
  int swz = (nwg % 8 == 0) ? ((f & 7) * (nwg >> 3) + (f >> 3)) : f;
  const int by = swz & 7, bx = swz >> 3;
  const int row0 = by * 256, col0 = bx * 256;

  const int srow = tid >> 3;
  const int sgch = ((tid & 7) ^ (srow & 7)) * 8;
  const int s7 = l15 & 7;
  const int ch0 = (l4 ^ s7) * 8;
  const int ch1 = ((4 + l4) ^ s7) * 8;

  f32x4 acc[8][4] = {};

#define STG_A(buf, half, kt)                                                        \
  do {                                                                              \
    const size_t k0_ = (size_t)(kt) * 64;                                           \
    async16(&As[buf][half][(wave * 8) * 64],                                        \
            A + (size_t)(row0 + (half) * 128 + srow) * K + k0_ + sgch);             \
    async16(&As[buf][half][(64 + wave * 8) * 64],                                   \
            A + (size_t)(row0 + (half) * 128 + 64 + srow) * K + k0_ + sgch);        \
  } while (0)
#define STG_B(buf, half, kt)                                                        \
  do {                                                                              \
    const size_t k0_ = (size_t)(kt) * 64;                                           \
    async16(&Bs[buf][half][(wave * 8) * 64],                                        \
            B + (size_t)(col0 + (half) * 128 + srow) * K + k0_ + sgch);             \
    async16(&Bs[buf][half][(64 + wave * 8) * 64],                                   \
            B + (size_t)(col0 + (half) * 128 + 64 + srow) * K + k0_ + sgch);        \
  } while (0)

#define PH(buf, q, STAGE, VM)                                                       \
  {                                                                                 \
    bf16x8 af[2][2];                                                                \
    _Pragma("unroll") for (int e = 0; e < 2; ++e) {                                 \
      const u16* pa = &As[buf][wm][((2 * (q) + e) * 16 + l15) * 64];                \
      af[e][0] = *(const bf16x8*)(pa + ch0);                                        \
      af[e][1] = *(const bf16x8*)(pa + ch1);                                        \
    }                                                                               \
    if ((q) == 0) {                                                                 \
      _Pragma("unroll") for (int n = 0; n < 4; ++n) {                               \
        const u16* pb = &Bs[buf][wn >> 1][((wn & 1) * 64 + n * 16 + l15) * 64];     \
        bfr[n][0] = *(const bf16x8*)(pb + ch0);                                     \
        bfr[n][1] = *(const bf16x8*)(pb + ch1);                                     \
      }                                                                             \
    }                                                                               \
    VM;                                                                             \
    __builtin_amdgcn_s_barrier();                                                   \
    asm volatile("s_waitcnt lgkmcnt(0)" ::: "memory");                              \
    STAGE;                                                                          \
    __builtin_amdgcn_s_setprio(1);                                                  \
    _Pragma("unroll") for (int kk = 0; kk < 2; ++kk)                                \
      _Pragma("unroll") for (int e = 0; e < 2; ++e)                                 \
        _Pragma("unroll") for (int n = 0; n < 4; ++n)                               \
          acc[2 * (q) + e][n] = __builtin_amdgcn_mfma_f32_16x16x32_bf16(            \
              af[e][kk], bfr[n][kk], acc[2 * (q) + e][n], 0, 0, 0);                 \
    __builtin_amdgcn_s_setprio(0);                                                  \
  }
#define VM2 asm volatile("s_waitcnt vmcnt(2)" ::: "memory")
#define VM0 asm volatile("s_waitcnt vmcnt(0)" ::: "memory")
#define VMNONE

  const int nkt = K >> 6;
  const int niter = nkt >> 1;

  STG_A(0, 0, 0); STG_A(0, 1, 0);
  STG_B(0, 0, 0); STG_B(0, 1, 0);
  STG_B(1, 0, 1); STG_B(1, 1, 1);
  asm volatile("s_waitcnt vmcnt(4)" ::: "memory");
  __builtin_amdgcn_s_barrier();

  for (int i = 0; i + 1 < niter; ++i) {
    const int t1 = 2 * i + 1, t2 = 2 * i + 2, t3 = 2 * i + 3;
    bf16x8 bfr[4][2];
    PH(0, 0, STG_A(1, 0, t1), VMNONE)
    PH(0, 1, STG_A(1, 1, t1), VMNONE)
    PH(0, 2, STG_B(0, 0, t2), VMNONE)
    PH(0, 3, STG_B(0, 1, t2), VM2)
    PH(1, 0, STG_A(0, 0, t2), VMNONE)
    PH(1, 1, STG_A(0, 1, t2), VMNONE)
    PH(1, 2, STG_B(1, 0, t3), VMNONE)
    PH(1, 3, STG_B(1, 1, t3), VM2)
  }
  {
    const int t1 = nkt - 1;
    bf16x8 bfr[4][2];
    PH(0, 0, STG_A(1, 0, t1), VMNONE)
    PH(0, 1, STG_A(1, 1, t1), VMNONE)
    PH(0, 2, ((void)0), VMNONE)
    PH(0, 3, ((void)0), VM0)
    PH(1, 0, ((void)0), VMNONE)
    PH(1, 1, ((void)0), VMNONE)
    PH(1, 2, ((void)0), VMNONE)
    PH(1, 3, ((void)0), VMNONE)
  }

  if (Cb) {
#pragma unroll
    for (int m = 0; m < 8; ++m)
#pragma unroll
      for (int n = 0; n < 4; ++n)
#pragma unroll
        for (int r = 0; r < 4; ++r) {
          int row = row0 + wm * 128 + m * 16 + l4 * 4 + r;
          int col = col0 + wn * 64 + n * 16 + l15;
          Cb[(size_t)row * N + col] = f2bf(acc[m][n][r]);
        }
  } else {
#pragma unroll
    for (int m = 0; m < 8; ++m)
#pragma unroll
      for (int n = 0; n < 4; ++n)
#pragma unroll
        for (int r = 0; r < 4; ++r) {
          int row = row0 + wm * 128 + m * 16 + l4 * 4 + r;
          int col = col0 + wn * 64 + n * 16 + l15;
          C[(size_t)row * N + col] = acc[m][n][r];
        }
  }
#undef STG_A
#undef STG_B
#undef PH
#undef VM2
#undef VM0
#undef VMNONE
}

// ---------- RoPE (neox) + per-head RMSNorm (bf16 qkv input) ----------
__global__ void k_rope_norm(const u16* __restrict__ qkv, const int* __restrict__ pos,
                            const float* __restrict__ wqk,
                            u16* __restrict__ qo, u16* __restrict__ ko) {
  const int wid = (blockIdx.x * blockDim.x + threadIdx.x) >> 6;
  const int lane = threadIdx.x & 63;
  const int s = wid / 48;
  const int r = wid - s * 48;
  const u16* src;
  u16* dst;
  const bool isq = (r < NHEAD);
  if (isq) {
    src = qkv + (size_t)s * QKV_COLS + r * HD;
    dst = qo + (size_t)s * (NHEAD * HD) + r * HD;
  } else {
    int kv = r - NHEAD;
    src = qkv + (size_t)s * QKV_COLS + HID + kv * HD;
    dst = ko + (size_t)s * (NKVH * HD) + kv * HD;
  }
  float x1 = bf2f(src[lane]), x2 = bf2f(src[lane + 64]);
  float p = (float)pos[s];
  float ang = p * exp2f(-(float)lane * (18.931568569324174f / 64.0f));
  float sn, cs;
  sincosf(ang, &sn, &cs);
  float y1 = x1 * cs - x2 * sn;
  float y2 = x2 * cs + x1 * sn;
  float ss = y1 * y1 + y2 * y2;
#pragma unroll
  for (int off = 32; off > 0; off >>= 1) ss += __shfl_xor(ss, off);
  float rms = rsqrtf(ss * (1.0f / 128.0f) + 1e-5f);
  float sc = isq ? 0.08838834764831843f : 1.0f;
  dst[lane] = f2bf(y1 * rms * wqk[lane] * sc);
  dst[lane + 64] = f2bf(y2 * rms * wqk[lane + 64] * sc);
}

// ---------- V: bf16 qkv [s][6144 + kvh*128 + d] -> Vt[kvh][d][s] ----------
__global__ void k_vtrans(const u16* __restrict__ qkv, u16* __restrict__ vt) {
  __shared__ u16 t[32][132];   // pad 4 elems (8B): col-read stride 264B -> 2-way (free)
  const int s0 = blockIdx.x * 32;
  const int kv = blockIdx.y;
  for (int i = threadIdx.x; i < 32 * 128; i += 256) {
    int sr = i >> 7, d = i & 127;
    t[sr][d] = qkv[(size_t)(s0 + sr) * QKV_COLS + (HID + NKVH * HD) + kv * HD + d];
  }
  __syncthreads();
  for (int i = threadIdx.x; i < 32 * 128; i += 256) {
    int d = i >> 5, sc = i & 31;
    vt[((size_t)kv * HD + d) * S_LEN + s0 + sc] = t[sc][d];
  }
}

// ---------- causal GQA flash attention: persistent blocks + atomic LPT queue ----------
__global__ __launch_bounds__(256, 2)
void k_attn(const u16* __restrict__ Q, const u16* __restrict__ Kb,
            const u16* __restrict__ Vt, u16* __restrict__ ctx,
            int* __restrict__ counter) {
  __shared__ __align__(16) u16 Ks[2][KVBLK * HD];
  __shared__ __align__(16) u16 Vs[2][HD * KVBLK];
  __shared__ int s_item;
  const int lane = threadIdx.x & 63;
  const int wave = threadIdx.x >> 6;
  const int l15 = lane & 15, l4 = lane >> 4;
  const int l7 = lane & 7, l8 = lane >> 3;

#define STAGE_KV(KT, BUF, KVH)                                                      \
  do {                                                                             \
    const int key0_ = (KT) * KVBLK;                                                \
    _Pragma("unroll")                                                              \
    for (int i = 0; i < 4; ++i) {                                                  \
      int krow = wave * 16 + i * 4 + l4;                                           \
      int kchunk = l15 ^ (krow & 7);                                               \
      async16(&Ks[BUF][(wave * 16 + i * 4) * HD],                                  \
              Kb + (size_t)(key0_ + krow) * (NKVH * HD) + (KVH) * HD + kchunk * 8);\
    }                                                                              \
    _Pragma("unroll")                                                              \
    for (int i = 0; i < 4; ++i) {                                                  \
      int vrow = wave * 32 + i * 8 + l8;                                           \
      int vchunk = l7 ^ (vrow & 7);                                                \
      async16(&Vs[BUF][(wave * 32 + i * 8) * KVBLK],                               \
              Vt + (size_t)((KVH) * HD + vrow) * S_LEN + key0_ + vchunk * 8);      \
    }                                                                              \
  } while (0)

#define VM8 asm volatile("s_waitcnt vmcnt(8)" ::: "memory")
#define VM0 asm volatile("s_waitcnt vmcnt(0)" ::: "memory")
#define BAR __builtin_amdgcn_s_barrier(); __builtin_amdgcn_sched_barrier(0)

#define COMPUTE(BUF, KT)                                                           \
  {                                                                                \
    const int key0 = (KT) * KVBLK;                                                 \
    f32x4 sa[2][4] = {};                                                           \
    _Pragma("unroll")                                                              \
    for (int c = 0; c < 4; ++c) {                                                  \
      _Pragma("unroll")                                                            \
      for (int n = 0; n < 4; ++n) {                                                \
        const int krow = n * 16 + l15;                                             \
        bf16x8 kf = *(const bf16x8*)(&Ks[BUF][krow * HD + ((c * 4 + l4) ^ (krow & 7)) * 8]); \
        sa[0][n] = __builtin_amdgcn_mfma_f32_16x16x32_bf16(kf, qf[0][c], sa[0][n], 0, 0, 0); \
        sa[1][n] = __builtin_amdgcn_mfma_f32_16x16x32_bf16(kf, qf[1][c], sa[1][n], 0, 0, 0); \
      }                                                                            \
    }                                                                              \
    const bool domask = (key0 + KVBLK) > qt * QBLK;                                \
    bf16x8 pa[2][2];                                                               \
    _Pragma("unroll")                                                              \
    for (int m2 = 0; m2 < 2; ++m2) {                                               \
      const int qrow = qrow0 + m2 * 16 + l15;                                      \
      if (domask) {                                                                \
        _Pragma("unroll")                                                          \
        for (int n = 0; n < 4; ++n)                                                \
          _Pragma("unroll")                                                        \
          for (int r = 0; r < 4; ++r)                                              \
            if (key0 + n * 16 + l4 * 4 + r > qrow) sa[m2][n][r] = -1e30f;          \
      }                                                                            \
      float mx = sa[m2][0][0];                                                     \
      _Pragma("unroll")                                                            \
      for (int n = 0; n < 4; ++n)                                                  \
        _Pragma("unroll")                                                          \
        for (int r = 0; r < 4; ++r) mx = fmaxf(mx, sa[m2][n][r]);                  \
      mx = fmaxf(mx, __shfl_xor(mx, 16));                                          \
      mx = fmaxf(mx, __shfl_xor(mx, 32));                                          \
      const float mnew = fmaxf(m_run[m2], mx);                                     \
      const float corr = __expf(m_run[m2] - mnew);                                 \
      m_run[m2] = mnew;                                                            \
      float p[4][4];                                                               \
      float sum = 0.f;                                                             \
      _Pragma("unroll")                                                            \
      for (int n = 0; n < 4; ++n)                                                  \
        _Pragma("unroll")                                                          \
        for (int r = 0; r < 4; ++r) { p[n][r] = __expf(sa[m2][n][r] - mnew); sum += p[n][r]; } \
      sum += __shfl_xor(sum, 16);                                                  \
      sum += __shfl_xor(sum, 32);                                                  \
      l_run[m2] = l_run[m2] * corr + sum;                                          \
      _Pragma("unroll")                                                            \
      for (int r = 0; r < 4; ++r) {                                                \
        float cc = __shfl(corr, (lane & 48) + ((lane >> 4) << 2) + r);             \
        _Pragma("unroll")                                                          \
        for (int f2 = 0; f2 < 8; ++f2) oacc[m2][f2][r] *= cc;                      \
      }                                                                            \
      unsigned pkk[4][2];                                                          \
      _Pragma("unroll")                                                            \
      for (int n = 0; n < 4; ++n)                                                  \
        _Pragma("unroll")                                                          \
        for (int hi = 0; hi < 2; ++hi)                                             \
          pkk[n][hi] = (unsigned)f2bf(p[n][2 * hi]) | ((unsigned)f2bf(p[n][2 * hi + 1]) << 16); \
      const int s0l = ((lane >> 4) & 1) * 32 + (lane & 15);                        \
      const bool hiSel = (lane & 32) != 0;                                         \
      _Pragma("unroll")                                                            \
      for (int c2 = 0; c2 < 2; ++c2) {                                             \
        unsigned ox[4];                                                            \
        _Pragma("unroll")                                                          \
        for (int i = 0; i < 4; ++i) {                                              \
          int srcl = s0l + ((i >> 1) << 4);                                        \
          unsigned lo = (unsigned)__shfl((int)pkk[2 * c2][i & 1], srcl);           \
          unsigned hi2 = (unsigned)__shfl((int)pkk[2 * c2 + 1][i & 1], srcl);      \
          ox[i] = hiSel ? hi2 : lo;                                                \
        }                                                                          \
        u32x4 tmp = {ox[0], ox[1], ox[2], ox[3]};                                  \
        pa[m2][c2] = __builtin_bit_cast(bf16x8, tmp);                              \
      }                                                                            \
    }                                                                              \
    _Pragma("unroll")                                                              \
    for (int c2 = 0; c2 < 2; ++c2) {                                               \
      _Pragma("unroll")                                                            \
      for (int f2 = 0; f2 < 8; ++f2) {                                             \
        const int vrow = f2 * 16 + l15;                                            \
        bf16x8 vf = *(const bf16x8*)(&Vs[BUF][vrow * KVBLK + ((c2 * 4 + l4) ^ (vrow & 7)) * 8]); \
        oacc[0][f2] = __builtin_amdgcn_mfma_f32_16x16x32_bf16(pa[0][c2], vf, oacc[0][f2], 0, 0, 0); \
        oacc[1][f2] = __builtin_amdgcn_mfma_f32_16x16x32_bf16(pa[1][c2], vf, oacc[1][f2], 0, 0, 0); \
      }                                                                            \
    }                                                                              \
  }

  for (;;) {
    if (threadIdx.x == 0) s_item = atomicAdd(counter, 1);
    __syncthreads();   // also orders previous item's LDS reads before restage
    const int item = s_item;
    if (item >= NITEMS) break;
    const int qt = (NQT - 1) - item / NHEAD;   // heaviest-first (LPT)
    const int h = item % NHEAD;
    const int kvh = h / GQA;
    const int qrow0 = qt * QBLK + wave * 32;

    bf16x8 qf[2][4];
#pragma unroll
    for (int c = 0; c < 4; ++c)
#pragma unroll
      for (int m2 = 0; m2 < 2; ++m2)
        qf[m2][c] = *(const bf16x8*)(Q + (size_t)(qrow0 + m2 * 16 + l15) * HID + h * HD + c * 32 + l4 * 8);

    float m_run[2] = {-1e30f, -1e30f};
    float l_run[2] = {0.f, 0.f};
    f32x4 oacc[2][8] = {};

    const int nt = 2 * qt + 2;

    STAGE_KV(0, 0, kvh);
    STAGE_KV(1, 1, kvh);

    int t = 0;
    for (; t + 2 < nt; t += 2) {
      VM8; BAR;
      COMPUTE(0, t)
      BAR;
      STAGE_KV(t + 2, 0, kvh);
      VM8; BAR;
      COMPUTE(1, t + 1)
      BAR;
      if (t + 3 < nt) STAGE_KV(t + 3, 1, kvh);
    }
    VM8; BAR;
    COMPUTE(0, nt - 2)
    VM0; BAR;
    COMPUTE(1, nt - 1)

#pragma unroll
    for (int m2 = 0; m2 < 2; ++m2)
#pragma unroll
      for (int r = 0; r < 4; ++r) {
        float li = 1.0f / __shfl(l_run[m2], (lane & 48) + ((lane >> 4) << 2) + r);
        int row = qrow0 + m2 * 16 + l4 * 4 + r;
#pragma unroll
        for (int f2 = 0; f2 < 8; ++f2)
          ctx[(size_t)row * HID + h * HD + f2 * 16 + l15] = f2bf(oacc[m2][f2][r] * li);
      }
  }
#undef STAGE_KV
#undef VM8
#undef VM0
#undef BAR
#undef COMPUTE
}

extern "C" void kernel_launch(void* const* d_in, const int* in_sizes, int n_in,
                              void* d_out, int out_size, void* d_ws, size_t ws_size,
                              hipStream_t stream) {
  (void)in_sizes; (void)n_in; (void)out_size; (void)ws_size;
  const int* positions = (const int*)d_in[0];
  const float* hs = (const float*)d_in[1];
  const float* Wqkv = (const float*)d_in[2];
  const float* Wo = (const float*)d_in[3];
  const float* wqk = (const float*)d_in[4];
  float* out = (float*)d_out;

  char* ws = (char*)d_ws;
  u16* Wqkv_b = (u16*)ws;                  // [0, 73400320)  dead after GEMM1
  u16* q_b   = (u16*)ws;                   // reuse: [0, 20971520)
  u16* k_b   = (u16*)(ws + 20971520);      // [.., 25165824)
  u16* vt_b  = (u16*)(ws + 25165824);      // [.., 29360128)
  int* cnt   = (int*)(ws + 29360128);      // 4 B (dead Wqkv region at attn time)
  u16* Wo_b  = (u16*)(ws + 73400320);      // [.., 125829120)
  u16* hs_b  = (u16*)(ws + 125829120);     // [.., 146800640)  dead after GEMM1
  u16* ctx_b = hs_b;                       // reuse
  u16* qkv_b = (u16*)(ws + 146800640);     // bf16 qkv: [.., 176160768)

  k_f32_to_bf16<<<2048, 256, 0, stream>>>((const float4*)hs, (uint2*)hs_b, (S_LEN * HID) / 4);
  k_f32_to_bf16<<<2048, 256, 0, stream>>>((const float4*)Wqkv, (uint2*)Wqkv_b, (QKV_COLS * HID) / 4);
  k_f32_to_bf16<<<2048, 256, 0, stream>>>((const float4*)Wo, (uint2*)Wo_b, (HID * HID) / 4);

  k_gemm256<<<dim3((QKV_COLS / 256) * (S_LEN / 256)), 512, 0, stream>>>(
      hs_b, Wqkv_b, (float*)nullptr, qkv_b, S_LEN, QKV_COLS, HID);

  k_rope_norm<<<(S_LEN * 48) / 4, 256, 0, stream>>>(qkv_b, positions, wqk, q_b, k_b);
  k_vtrans<<<dim3(S_LEN / 32, NKVH), 256, 0, stream>>>(qkv_b, vt_b);

  hipMemsetAsync(cnt, 0, 4, stream);
  k_attn<<<dim3(512), 256, 0, stream>>>(q_b, k_b, vt_b, ctx_b, cnt);

  k_gemm256<<<dim3((HID / 256) * (S_LEN / 256)), 512, 0, stream>>>(
      ctx_b, Wo_b, out, (u16*)nullptr, S_LEN, HID, HID);
}